// Round 15
// baseline (35.393 us; speedup 1.0000x reference)
//
#include <hip/hip_runtime.h>
#include <stdint.h>

#define KDIM 2048
#define NEXP 64
#define MT   64              // tokens per block
#define KC   64              // k per chunk (two MFMA k-steps)  [R15: 32 -> 64]
#define NTHR 256             // 4 waves: 2 token-halves x 2 expert-halves
#define NTOK 16384

typedef _Float16 half8 __attribute__((ext_vector_type(8)));
typedef __fp16  fp16x2 __attribute__((ext_vector_type(2)));
typedef float f32x4 __attribute__((ext_vector_type(4)));

// swizzled byte offset within one [64 rows][128 B] LDS plane:
// row-stride 128 B aligns all rows to bank 0; XOR row[2:0] into addr bits [6:4]
// spreads the 8 16B-slots so b128 reads/writes land 8 lanes per 4-bank group, even.
__device__ __forceinline__ int swz128(int row, int byte_in_row) {
    return (row << 7) + (byte_in_row ^ ((row & 7) << 4));
}

__device__ __forceinline__ uint32_t pkrtz(float a, float b) {
    fp16x2 h = __builtin_amdgcn_cvt_pkrtz(a, b);
    return __builtin_bit_cast(uint32_t, h);
}

// truncate-split 4 f32 -> (4 f16 hi, 4 f16 lo) as two uint2 (R7/R9/R14-proven numerics)
__device__ __forceinline__ void split4(float4 v, uint2* hv, uint2* lv) {
    float y[4] = {v.x, v.y, v.z, v.w};
    uint32_t hw[2], lw[2];
    #pragma unroll
    for (int i = 0; i < 2; ++i) {
        float y0 = y[2 * i], y1 = y[2 * i + 1];
        float h0 = __builtin_bit_cast(float, __builtin_bit_cast(uint32_t, y0) & 0xFFFFE000u);
        float h1 = __builtin_bit_cast(float, __builtin_bit_cast(uint32_t, y1) & 0xFFFFE000u);
        hw[i] = pkrtz(h0, h1);
        lw[i] = pkrtz(y0 - h0, y1 - h1);
    }
    hv->x = hw[0]; hv->y = hw[1];
    lv->x = lw[0]; lv->y = lw[1];
}

// counted waits + raw barrier (R8-proven): loads stay in flight across barriers
#define VMCNT8() do { asm volatile("s_waitcnt vmcnt(8)" ::: "memory"); \
                      __builtin_amdgcn_sched_barrier(0); } while (0)
#define VMCNT0() do { asm volatile("s_waitcnt vmcnt(0)" ::: "memory"); \
                      __builtin_amdgcn_sched_barrier(0); } while (0)
#define LGKM_BAR() do { asm volatile("s_waitcnt lgkmcnt(0)" ::: "memory"); \
                        __builtin_amdgcn_sched_barrier(0);                 \
                        __builtin_amdgcn_s_barrier();                      \
                        __builtin_amdgcn_sched_barrier(0); } while (0)

// Split-K router, on-the-fly W split: block (tg, kh) does k in [kh*1024, +1024)
__global__ __launch_bounds__(NTHR) void router_kernel(const float* __restrict__ x,
                                                      const float* __restrict__ W,
                                                      float* __restrict__ partials) {
    __shared__ char AsB[2][2][8192];   // [buf][h/l] x-tiles: 64 tok x 64 k f16 (32 KB)
    __shared__ char BsB[2][2][8192];   // [buf][h/l] w-tiles: 64 exp x 64 k f16 (32 KB)

    const int tid  = threadIdx.x;
    const int lane = tid & 63;
    const int wave = tid >> 6;
    const int wm   = wave >> 1;        // token half  (32 tok)
    const int wn   = wave & 1;         // expert half (32 exp)
    const int kh   = blockIdx.x & 1;   // K-half
    const int tb   = (blockIdx.x >> 1) * MT;
    const int kb0  = kh * (KDIM / 2);  // k offset of this half

    // ---- staging coords: thread owns 16 consecutive f32 of one row ----
    const int srow = tid >> 2;                  // 0..63 (token row AND expert row)
    const int sseg = tid & 3;                   // 16-f32 segment
    const float* xsrc = x + (size_t)(tb + srow) * KDIM + kb0 + sseg * 16;
    const float* wsrc = W + (size_t)srow * KDIM + kb0 + sseg * 16;
    const int offA = swz128(srow, sseg * 32);
    const int offB = swz128(srow, sseg * 32 + 16);

    // ---- compute-side read offsets (2 k-steps per chunk) ----
    const int kb = lane >> 4;
    int aoff0[2], aoff1[2], boff0[2], boff1[2];
    #pragma unroll
    for (int ks = 0; ks < 2; ++ks) {
        const int byt = ks * 64 + kb * 16;
        aoff0[ks] = swz128(wm * 32 +      (lane & 15), byt);
        aoff1[ks] = swz128(wm * 32 + 16 + (lane & 15), byt);
        boff0[ks] = swz128(wn * 32 +      (lane & 15), byt);
        boff1[ks] = swz128(wn * 32 + 16 + (lane & 15), byt);
    }

    f32x4 acc[2][2];
    #pragma unroll
    for (int i = 0; i < 2; ++i)
        #pragma unroll
        for (int j = 0; j < 2; ++j)
            acc[i][j] = (f32x4){0.f, 0.f, 0.f, 0.f};

    // two NAMED register prefetch sets (4 x-float4 + 4 W-float4 each)
    float4 AX[4], AW[4];
    float4 BX[4], BW[4];

#define LOADM(XA, WA, c)                                                     \
    do {                                                                     \
        _Pragma("unroll")                                                    \
        for (int i2 = 0; i2 < 4; ++i2)                                       \
            XA[i2] = *reinterpret_cast<const float4*>(xsrc + (c) * KC + i2 * 4); \
        _Pragma("unroll")                                                    \
        for (int i2 = 0; i2 < 4; ++i2)                                       \
            WA[i2] = *reinterpret_cast<const float4*>(wsrc + (c) * KC + i2 * 4); \
    } while (0)

    auto STORE = [&](int b, const float4* X, const float4* Wv) {
        uint2 h0, l0, h1, l1;
        // x -> AsB
        split4(X[0], &h0, &l0); split4(X[1], &h1, &l1);
        uint4 H = {h0.x, h0.y, h1.x, h1.y};
        uint4 L = {l0.x, l0.y, l1.x, l1.y};
        *reinterpret_cast<uint4*>(&AsB[b][0][0] + offA) = H;
        *reinterpret_cast<uint4*>(&AsB[b][1][0] + offA) = L;
        split4(X[2], &h0, &l0); split4(X[3], &h1, &l1);
        H = (uint4){h0.x, h0.y, h1.x, h1.y};
        L = (uint4){l0.x, l0.y, l1.x, l1.y};
        *reinterpret_cast<uint4*>(&AsB[b][0][0] + offB) = H;
        *reinterpret_cast<uint4*>(&AsB[b][1][0] + offB) = L;
        // W -> BsB
        split4(Wv[0], &h0, &l0); split4(Wv[1], &h1, &l1);
        H = (uint4){h0.x, h0.y, h1.x, h1.y};
        L = (uint4){l0.x, l0.y, l1.x, l1.y};
        *reinterpret_cast<uint4*>(&BsB[b][0][0] + offA) = H;
        *reinterpret_cast<uint4*>(&BsB[b][1][0] + offA) = L;
        split4(Wv[2], &h0, &l0); split4(Wv[3], &h1, &l1);
        H = (uint4){h0.x, h0.y, h1.x, h1.y};
        L = (uint4){l0.x, l0.y, l1.x, l1.y};
        *reinterpret_cast<uint4*>(&BsB[b][0][0] + offB) = H;
        *reinterpret_cast<uint4*>(&BsB[b][1][0] + offB) = L;
    };

    auto COMPUTE = [&](int b) {
        #pragma unroll
        for (int ks = 0; ks < 2; ++ks) {
            half8 ah0 = *reinterpret_cast<const half8*>(&AsB[b][0][0] + aoff0[ks]);
            half8 ah1 = *reinterpret_cast<const half8*>(&AsB[b][0][0] + aoff1[ks]);
            half8 al0 = *reinterpret_cast<const half8*>(&AsB[b][1][0] + aoff0[ks]);
            half8 al1 = *reinterpret_cast<const half8*>(&AsB[b][1][0] + aoff1[ks]);
            half8 bh0 = *reinterpret_cast<const half8*>(&BsB[b][0][0] + boff0[ks]);
            half8 bh1 = *reinterpret_cast<const half8*>(&BsB[b][0][0] + boff1[ks]);
            half8 bl0 = *reinterpret_cast<const half8*>(&BsB[b][1][0] + boff0[ks]);
            half8 bl1 = *reinterpret_cast<const half8*>(&BsB[b][1][0] + boff1[ks]);
            acc[0][0] = __builtin_amdgcn_mfma_f32_16x16x32_f16(ah0, bh0, acc[0][0], 0, 0, 0);
            acc[0][0] = __builtin_amdgcn_mfma_f32_16x16x32_f16(al0, bh0, acc[0][0], 0, 0, 0);
            acc[0][0] = __builtin_amdgcn_mfma_f32_16x16x32_f16(ah0, bl0, acc[0][0], 0, 0, 0);
            acc[0][1] = __builtin_amdgcn_mfma_f32_16x16x32_f16(ah0, bh1, acc[0][1], 0, 0, 0);
            acc[0][1] = __builtin_amdgcn_mfma_f32_16x16x32_f16(al0, bh1, acc[0][1], 0, 0, 0);
            acc[0][1] = __builtin_amdgcn_mfma_f32_16x16x32_f16(ah0, bl1, acc[0][1], 0, 0, 0);
            acc[1][0] = __builtin_amdgcn_mfma_f32_16x16x32_f16(ah1, bh0, acc[1][0], 0, 0, 0);
            acc[1][0] = __builtin_amdgcn_mfma_f32_16x16x32_f16(al1, bh0, acc[1][0], 0, 0, 0);
            acc[1][0] = __builtin_amdgcn_mfma_f32_16x16x32_f16(ah1, bl0, acc[1][0], 0, 0, 0);
            acc[1][1] = __builtin_amdgcn_mfma_f32_16x16x32_f16(ah1, bh1, acc[1][1], 0, 0, 0);
            acc[1][1] = __builtin_amdgcn_mfma_f32_16x16x32_f16(al1, bh1, acc[1][1], 0, 0, 0);
            acc[1][1] = __builtin_amdgcn_mfma_f32_16x16x32_f16(ah1, bl1, acc[1][1], 0, 0, 0);
        }
    };

    // ---- prologue: 16 loads in flight; vmcnt(8) = set A landed ----
    LOADM(AX, AW, 0);
    LOADM(BX, BW, 1);
    VMCNT8();
    STORE(0, AX, AW);
    LGKM_BAR();

    // ---- main loop: chunks 0..13 of 16, unrolled x2 for static parity ----
    for (int q = 0; q < 7; ++q) {
        COMPUTE(0);
        LOADM(AX, AW, 2 * q + 2);
        VMCNT8();                    // chunk 2q+1 (set B) landed; 2q+2 still flying
        STORE(1, BX, BW);
        LGKM_BAR();
        COMPUTE(1);
        LOADM(BX, BW, 2 * q + 3);
        VMCNT8();
        STORE(0, AX, AW);
        LGKM_BAR();
    }
    // ---- tail: chunks 14, 15 ----
    COMPUTE(0);
    VMCNT0();
    STORE(1, BX, BW);
    LGKM_BAR();
    COMPUTE(1);

    // ---- epilogue: write partial scores (truncate-split => no rescale) ----
    float* pbase = partials + (size_t)kh * NTOK * NEXP;
    #pragma unroll
    for (int m = 0; m < 2; ++m)
        #pragma unroll
        for (int n = 0; n < 2; ++n)
            #pragma unroll
            for (int r = 0; r < 4; ++r) {
                int tok = wm * 32 + m * 16 + (lane >> 4) * 4 + r;   // C/D: row=(lane>>4)*4+reg
                int e   = wn * 32 + n * 16 + (lane & 15);           //      col=lane&15  (m89)
                pbase[(size_t)(tb + tok) * NEXP + e] = acc[m][n][r];
            }
#undef LOADM
}

// sum the two K-half partials and take top-2 per token
__global__ __launch_bounds__(256) void reduce_kernel(const float* __restrict__ partials,
                                                     float* __restrict__ out_w,
                                                     float* __restrict__ out_i) {
    const int t = blockIdx.x * 256 + threadIdx.x;   // token
    const float4* p0 = reinterpret_cast<const float4*>(partials + (size_t)t * NEXP);
    const float4* p1 = reinterpret_cast<const float4*>(partials + (size_t)NTOK * NEXP + (size_t)t * NEXP);
    float s[NEXP];
    #pragma unroll
    for (int j = 0; j < NEXP / 4; ++j) {
        float4 a = p0[j];
        float4 b = p1[j];
        s[4 * j + 0] = a.x + b.x;
        s[4 * j + 1] = a.y + b.y;
        s[4 * j + 2] = a.z + b.z;
        s[4 * j + 3] = a.w + b.w;
    }
    float m1 = -1e30f, m2 = -1e30f;
    int i1 = 0, i2 = 0;
    // strict '>' keeps the lower index on ties, matching jax.lax.top_k
    #pragma unroll
    for (int e = 0; e < NEXP; ++e) {
        float v = s[e];
        if (v > m1) { m2 = m1; i2 = i1; m1 = v; i1 = e; }
        else if (v > m2) { m2 = v; i2 = e; }
    }
    out_w[t * 2 + 0] = m1;
    out_w[t * 2 + 1] = m2;
    out_i[t * 2 + 0] = (float)i1;
    out_i[t * 2 + 1] = (float)i2;
}

extern "C" void kernel_launch(void* const* d_in, const int* in_sizes, int n_in,
                              void* d_out, int out_size, void* d_ws, size_t ws_size,
                              hipStream_t stream) {
    const float* x = (const float*)d_in[0];   // [16384, 2048] f32
    const float* W = (const float*)d_in[1];   // [64, 2048]   f32
    float* out = (float*)d_out;               // [16384*2 weights][16384*2 indices]

    const int n_tokens = in_sizes[0] / KDIM;  // 16384
    float* partials = (float*)d_ws;           // 2 x 4 MB

    hipLaunchKernelGGL(router_kernel, dim3((n_tokens / MT) * 2), dim3(NTHR), 0, stream,
                       x, W, partials);
    hipLaunchKernelGGL(reduce_kernel, dim3(n_tokens / 256), dim3(256), 0, stream,
                       partials, out, out + 2 * (size_t)n_tokens);
}

// Round 16
// 31.195 us; speedup vs baseline: 1.1346x; 1.1346x over previous
//
#include <hip/hip_runtime.h>
#include <stdint.h>

#define KDIM 2048
#define NEXP 64
#define MT   64              // tokens per block
#define KC   32              // k per chunk (one MFMA-K)
#define NTHR 512             // 8 waves = 2 K-half groups x (2 token-halves x 2 expert-halves)
#define NTOK 16384

typedef _Float16 half8 __attribute__((ext_vector_type(8)));
typedef __fp16  fp16x2 __attribute__((ext_vector_type(2)));
typedef float f32x4 __attribute__((ext_vector_type(4)));

// swizzled byte offset within one [64 rows][64B] LDS tensor
__device__ __forceinline__ int swz(int row, int byte_in_row) {
    return ((row << 6) + byte_in_row) ^ ((row & 14) << 3);
}

__device__ __forceinline__ uint32_t pkrtz(float a, float b) {
    fp16x2 h = __builtin_amdgcn_cvt_pkrtz(a, b);
    return __builtin_bit_cast(uint32_t, h);
}

// truncate-split 4 f32 -> (4 f16 hi, 4 f16 lo) as two uint2 (R14-proven numerics)
__device__ __forceinline__ void split4(float4 v, uint2* hv, uint2* lv) {
    float y[4] = {v.x, v.y, v.z, v.w};
    uint32_t hw[2], lw[2];
    #pragma unroll
    for (int i = 0; i < 2; ++i) {
        float y0 = y[2 * i], y1 = y[2 * i + 1];
        float h0 = __builtin_bit_cast(float, __builtin_bit_cast(uint32_t, y0) & 0xFFFFE000u);
        float h1 = __builtin_bit_cast(float, __builtin_bit_cast(uint32_t, y1) & 0xFFFFE000u);
        hw[i] = pkrtz(h0, h1);
        lw[i] = pkrtz(y0 - h0, y1 - h1);
    }
    hv->x = hw[0]; hv->y = hw[1];
    lv->x = lw[0]; lv->y = lw[1];
}

// counted waits + raw barrier (R8/R14-proven): loads stay in flight across barriers
#define VMCNT4() do { asm volatile("s_waitcnt vmcnt(4)" ::: "memory"); \
                      __builtin_amdgcn_sched_barrier(0); } while (0)
#define VMCNT0() do { asm volatile("s_waitcnt vmcnt(0)" ::: "memory"); \
                      __builtin_amdgcn_sched_barrier(0); } while (0)
#define LGKM_BAR() do { asm volatile("s_waitcnt lgkmcnt(0)" ::: "memory"); \
                        __builtin_amdgcn_sched_barrier(0);                 \
                        __builtin_amdgcn_s_barrier();                      \
                        __builtin_amdgcn_sched_barrier(0); } while (0)

// Fused split-K router: waves 0-3 do k in [0,1024), waves 4-7 do [1024,2048);
// per-group loop is byte-identical to R14's; combine + top-2 in LDS at the end.
__global__ __launch_bounds__(NTHR) void router_kernel(const float* __restrict__ x,
                                                      const float* __restrict__ W,
                                                      float* __restrict__ out_w,
                                                      float* __restrict__ out_i) {
    __shared__ char AsB[2][2][2][4096];   // [grp][buf][h/l] x-tiles (32 KB)
    __shared__ char BsB[2][2][2][4096];   // [grp][buf][h/l] w-tiles (32 KB)

    const int tid  = threadIdx.x;
    const int lane = tid & 63;
    const int wave = tid >> 6;
    const int g    = wave >> 2;        // K-half group
    const int wm   = (wave >> 1) & 1;  // token half  (32 tok)
    const int wn   = wave & 1;         // expert half (32 exp)
    const int tidg = tid & 255;        // tid within group
    const int tb   = blockIdx.x * MT;
    const int kb0  = g * (KDIM / 2);   // k offset of this group's half

    // ---- staging coords (R14, with tidg/g) ----
    const int xrow0 = tidg >> 3;                // 0..31
    const int xseg  = tidg & 7;
    const float* xsrc0 = x + (size_t)(tb + xrow0) * KDIM + kb0 + xseg * 4;
    const float* xsrc1 = x + (size_t)(tb + xrow0 + 32) * KDIM + kb0 + xseg * 4;
    const int xoff0 = swz(xrow0, xseg * 8);
    const int xoff1 = swz(xrow0 + 32, xseg * 8);
    const int wrr = tidg >> 2;                  // expert row 0..63
    const int wss = tidg & 3;                   // 8-float segment
    const float* wsrc = W + (size_t)wrr * KDIM + kb0 + wss * 8;
    const int woff = swz(wrr, wss * 16);

    // ---- compute-side read offsets ----
    const int kb = lane >> 4;
    const int ra0 = wm * 32 + (lane & 15);
    const int rb0 = wn * 32 + (lane & 15);
    const int aoff0 = swz(ra0,      kb * 16);
    const int aoff1 = swz(ra0 + 16, kb * 16);
    const int boff0 = swz(rb0,      kb * 16);
    const int boff1 = swz(rb0 + 16, kb * 16);

    f32x4 acc[2][2];
    #pragma unroll
    for (int i = 0; i < 2; ++i)
        #pragma unroll
        for (int j = 0; j < 2; ++j)
            acc[i][j] = (f32x4){0.f, 0.f, 0.f, 0.f};

    // named register prefetch sets: x rows + raw f32 W segment
    float4 Ax0, Ax1, Aw0, Aw1;   // set A
    float4 Bx0, Bx1, Bw0, Bw1;   // set B

#define LOADM(X0, X1, W0, W1, c)                                           \
    do {                                                                   \
        X0 = *reinterpret_cast<const float4*>(xsrc0 + (c) * KC);           \
        X1 = *reinterpret_cast<const float4*>(xsrc1 + (c) * KC);           \
        W0 = *reinterpret_cast<const float4*>(wsrc + (c) * KC);            \
        W1 = *reinterpret_cast<const float4*>(wsrc + (c) * KC + 4);        \
    } while (0)

    auto STORE = [&](int b, float4 v0, float4 v1, float4 w0, float4 w1) {
        uint2 hv, lv;
        split4(v0, &hv, &lv);
        *reinterpret_cast<uint2*>(&AsB[g][b][0][0] + xoff0) = hv;
        *reinterpret_cast<uint2*>(&AsB[g][b][1][0] + xoff0) = lv;
        split4(v1, &hv, &lv);
        *reinterpret_cast<uint2*>(&AsB[g][b][0][0] + xoff1) = hv;
        *reinterpret_cast<uint2*>(&AsB[g][b][1][0] + xoff1) = lv;
        uint2 h0, l0, h1, l1;
        split4(w0, &h0, &l0);
        split4(w1, &h1, &l1);
        uint4 wh = {h0.x, h0.y, h1.x, h1.y};
        uint4 wl = {l0.x, l0.y, l1.x, l1.y};
        *reinterpret_cast<uint4*>(&BsB[g][b][0][0] + woff) = wh;
        *reinterpret_cast<uint4*>(&BsB[g][b][1][0] + woff) = wl;
    };

    auto COMPUTE = [&](int b) {
        half8 ah[2], al[2], bh[2], bl[2];
        ah[0] = *reinterpret_cast<const half8*>(&AsB[g][b][0][0] + aoff0);
        ah[1] = *reinterpret_cast<const half8*>(&AsB[g][b][0][0] + aoff1);
        al[0] = *reinterpret_cast<const half8*>(&AsB[g][b][1][0] + aoff0);
        al[1] = *reinterpret_cast<const half8*>(&AsB[g][b][1][0] + aoff1);
        bh[0] = *reinterpret_cast<const half8*>(&BsB[g][b][0][0] + boff0);
        bh[1] = *reinterpret_cast<const half8*>(&BsB[g][b][0][0] + boff1);
        bl[0] = *reinterpret_cast<const half8*>(&BsB[g][b][1][0] + boff0);
        bl[1] = *reinterpret_cast<const half8*>(&BsB[g][b][1][0] + boff1);
        #pragma unroll
        for (int m = 0; m < 2; ++m)
            #pragma unroll
            for (int n = 0; n < 2; ++n) {
                acc[m][n] = __builtin_amdgcn_mfma_f32_16x16x32_f16(ah[m], bh[n], acc[m][n], 0, 0, 0);
                acc[m][n] = __builtin_amdgcn_mfma_f32_16x16x32_f16(al[m], bh[n], acc[m][n], 0, 0, 0);
                acc[m][n] = __builtin_amdgcn_mfma_f32_16x16x32_f16(ah[m], bl[n], acc[m][n], 0, 0, 0);
            }
    };

    // ---- prologue ----
    LOADM(Ax0, Ax1, Aw0, Aw1, 0);
    LOADM(Bx0, Bx1, Bw0, Bw1, 1);
    VMCNT4();
    STORE(0, Ax0, Ax1, Aw0, Aw1);
    LGKM_BAR();

    // ---- main loop: chunks 0..29 of this half ----
    for (int q = 0; q < 15; ++q) {
        COMPUTE(0);
        LOADM(Ax0, Ax1, Aw0, Aw1, 2 * q + 2);
        VMCNT4();
        STORE(1, Bx0, Bx1, Bw0, Bw1);
        LGKM_BAR();
        COMPUTE(1);
        LOADM(Bx0, Bx1, Bw0, Bw1, 2 * q + 3);
        VMCNT4();
        STORE(0, Ax0, Ax1, Aw0, Aw1);
        LGKM_BAR();
    }
    // ---- tail: chunks 30, 31 ----
    COMPUTE(0);
    VMCNT0();
    STORE(1, Bx0, Bx1, Bw0, Bw1);
    LGKM_BAR();
    COMPUTE(1);

    // ---- combine the two K-halves in LDS, then top-2 ----
    __syncthreads();   // all staging reads done; LDS reusable
    float (*ss)[NEXP + 3] = reinterpret_cast<float (*)[NEXP + 3]>(&AsB[0][0][0][0]);  // 17.2 KB overlay
    if (g == 0) {
        #pragma unroll
        for (int m = 0; m < 2; ++m)
            #pragma unroll
            for (int n = 0; n < 2; ++n)
                #pragma unroll
                for (int r = 0; r < 4; ++r) {
                    int tok = wm * 32 + m * 16 + (lane >> 4) * 4 + r;   // C/D: row=(lane>>4)*4+reg
                    int e   = wn * 32 + n * 16 + (lane & 15);           //      col=lane&15 (m89)
                    ss[tok][e] = acc[m][n][r];
                }
    }
    __syncthreads();
    if (g == 1) {
        #pragma unroll
        for (int m = 0; m < 2; ++m)
            #pragma unroll
            for (int n = 0; n < 2; ++n)
                #pragma unroll
                for (int r = 0; r < 4; ++r) {
                    int tok = wm * 32 + m * 16 + (lane >> 4) * 4 + r;
                    int e   = wn * 32 + n * 16 + (lane & 15);
                    ss[tok][e] += acc[m][n][r];   // half0 + half1 (same order as R14 reduce)
                }
    }
    __syncthreads();

    if (tid < MT) {
        const int t = tid;
        float m1 = -1e30f, m2 = -1e30f;
        int i1 = 0, i2 = 0;
        // strict '>' keeps the lower index on ties, matching jax.lax.top_k
        #pragma unroll
        for (int e = 0; e < NEXP; ++e) {
            float v = ss[t][e];
            if (v > m1) { m2 = m1; i2 = i1; m1 = v; i1 = e; }
            else if (v > m2) { m2 = v; i2 = e; }
        }
        const int gt = tb + t;
        out_w[gt * 2 + 0] = m1;
        out_w[gt * 2 + 1] = m2;
        out_i[gt * 2 + 0] = (float)i1;
        out_i[gt * 2 + 1] = (float)i2;
    }
#undef LOADM
}

extern "C" void kernel_launch(void* const* d_in, const int* in_sizes, int n_in,
                              void* d_out, int out_size, void* d_ws, size_t ws_size,
                              hipStream_t stream) {
    const float* x = (const float*)d_in[0];   // [16384, 2048] f32
    const float* W = (const float*)d_in[1];   // [64, 2048]   f32
    float* out = (float*)d_out;               // [16384*2 weights][16384*2 indices]

    const int n_tokens = in_sizes[0] / KDIM;  // 16384

    hipLaunchKernelGGL(router_kernel, dim3(n_tokens / MT), dim3(NTHR), 0, stream,
                       x, W, out, out + 2 * (size_t)n_tokens);
}